// Round 4
// baseline (404.054 us; speedup 1.0000x reference)
//
#include <hip/hip_runtime.h>
#include <hip/hip_bf16.h>

typedef __bf16 bf16x8 __attribute__((ext_vector_type(8)));
typedef float f32x16 __attribute__((ext_vector_type(16)));

#define NQ     10
#define M_ROWS 16384
#define N_COLS 1024
#define K_DIM  4096

// ---------------------------------------------------------------- helpers
__device__ __forceinline__ void gload_lds16(const __hip_bfloat16* g, __hip_bfloat16* l) {
  __builtin_amdgcn_global_load_lds(
      (const __attribute__((address_space(1))) void*)g,
      (__attribute__((address_space(3))) void*)l,
      16, 0, 0);
}

// ---------------------------------------------------------------- prep (fused)
// blocks 0..4095: W2 fp32->bf16 ; blocks 4096..4111: W1 (4096x10) -> W1T (10x4096)
__global__ void __launch_bounds__(256) prep(const float* __restrict__ W1,
                                            float* __restrict__ W1T,
                                            const float* __restrict__ W2,
                                            __hip_bfloat16* __restrict__ W2b) {
  const int b = blockIdx.x;
  if (b < 4096) {
    int i = (b * 256 + threadIdx.x) * 4;
    float4 v = *(const float4*)(W2 + i);
    union { __hip_bfloat16 h[4]; uint2 u; } p;
    p.h[0] = __float2bfloat16(v.x);
    p.h[1] = __float2bfloat16(v.y);
    p.h[2] = __float2bfloat16(v.z);
    p.h[3] = __float2bfloat16(v.w);
    *(uint2*)(W2b + i) = p.u;
  } else {
    int f = (b - 4096) * 256 + threadIdx.x;
#pragma unroll
    for (int j = 0; j < NQ; j++)
      W1T[j * K_DIM + f] = W1[f * NQ + j];
  }
}

// ---------------------------------------------------------------- h = relu(q_out @ W1^T) bf16
// closed form: q[0] = prod_{j=1..9} cos; q[k] = prod_{j=0..k} cos
__global__ void __launch_bounds__(256) compute_h(const float* __restrict__ x,
                                                 const float* __restrict__ qp,
                                                 const float* __restrict__ W1T,
                                                 __hip_bfloat16* __restrict__ h) {
  __shared__ float qs[8][NQ];
  const int tid = threadIdx.x;
  const int r0 = blockIdx.x * 8;

  if (tid < 8 * NQ) {
    int r = tid / NQ, j = tid % NQ;
    qs[r][j] = cosf(x[(r0 + r) * NQ + j] + qp[j]);
  }
  __syncthreads();
  if (tid < 8) {
    float c[NQ];
#pragma unroll
    for (int j = 0; j < NQ; j++) c[j] = qs[tid][j];
    float pref = c[0];
    float prod19 = 1.f;
#pragma unroll
    for (int j = 1; j < NQ; j++) prod19 *= c[j];
    qs[tid][0] = prod19;
#pragma unroll
    for (int k = 1; k < NQ; k++) { pref *= c[k]; qs[tid][k] = pref; }
  }
  __syncthreads();

#pragma unroll 1
  for (int k = 0; k < 2; k++) {
    const int col0 = k * 2048 + tid * 8;
    float w[8][NQ];
#pragma unroll
    for (int j = 0; j < NQ; j++) {
      float4 a = *(const float4*)(W1T + j * K_DIM + col0);
      float4 b = *(const float4*)(W1T + j * K_DIM + col0 + 4);
      w[0][j] = a.x; w[1][j] = a.y; w[2][j] = a.z; w[3][j] = a.w;
      w[4][j] = b.x; w[5][j] = b.y; w[6][j] = b.z; w[7][j] = b.w;
    }
#pragma unroll
    for (int r = 0; r < 8; r++) {
      float q[NQ];
#pragma unroll
      for (int j = 0; j < NQ; j++) q[j] = qs[r][j];
      union { __hip_bfloat16 hh[8]; uint4 u; } pk;
#pragma unroll
      for (int c = 0; c < 8; c++) {
        float acc = 0.f;
#pragma unroll
        for (int j = 0; j < NQ; j++) acc = fmaf(q[j], w[c][j], acc);
        pk.hh[c] = __float2bfloat16(fmaxf(acc, 0.f));
      }
      *(uint4*)(h + (r0 + r) * K_DIM + col0) = pk.u;
    }
  }
}

// ---------------------------------------------------------------- C = A(MxK) * B(NxK)^T, bf16 in fp32 out
// 32x32x16 MFMA. A: global->LDS (XOR swizzle). B: DIRECT global->register
// fragments (16B contiguous, L2-resident), software-prefetched one K-step
// ahead. Halves the LDS-pipe load (previous binding constraint) and the
// barrier vmcnt drain.
__global__ void __launch_bounds__(256) gemm_bt(const __hip_bfloat16* __restrict__ A,
                                               const __hip_bfloat16* __restrict__ B,
                                               float* __restrict__ C) {
  __shared__ __align__(16) __hip_bfloat16 As[128 * 64];

  const int tid  = threadIdx.x;
  const int wave = tid >> 6;
  const int lane = tid & 63;
  const int l31  = lane & 31;
  const int l5   = lane >> 5;
  const int l7   = lane & 7;
  const int wm   = (wave & 1) * 64;
  const int wn   = (wave >> 1) * 64;

  // XCD decode, col0 SLOWEST within an XCD: resident blocks on an XCD share
  // one 128-col B slice (1 MB, L2-resident) while A streams.
  const int L    = blockIdx.x;
  const int xcd  = L & 7;
  const int idx  = L >> 3;                       // 0..127
  const int col0 = (idx >> 4) * 128;             // 8 col tiles, slow
  const int row0 = ((xcd << 4) | (idx & 15)) * 128;

  const int ldr = wave * 8 + (lane >> 3);
  const int ldc = ((l7 ^ (lane >> 3)) << 3);     // LDS[R][p] = global[R][p^(R&7)]

  // B fragment base: row = col0 + wn + nf*32 + l31, k = k0 + kki*16 + l5*8
  const __hip_bfloat16* Bp0 = B + (col0 + wn + l31) * K_DIM + l5 * 8;
  const __hip_bfloat16* Bp1 = Bp0 + 32 * K_DIM;

  f32x16 acc[2][2];
#pragma unroll
  for (int i = 0; i < 2; i++)
#pragma unroll
    for (int j = 0; j < 2; j++)
#pragma unroll
      for (int r = 0; r < 16; r++) acc[i][j][r] = 0.f;

  // prologue: B fragments for k0 = 0
  bf16x8 bb[2][4], bbn[2][4];
#pragma unroll
  for (int kki = 0; kki < 4; kki++) {
    bb[0][kki] = *(const bf16x8*)(Bp0 + kki * 16);
    bb[1][kki] = *(const bf16x8*)(Bp1 + kki * 16);
  }

  for (int k0 = 0; k0 < K_DIM; k0 += 64) {
    // stage A tile
#pragma unroll
    for (int i = 0; i < 4; i++)
      gload_lds16(A + (row0 + i * 32 + ldr) * K_DIM + k0 + ldc,
                  As + (i * 32 + wave * 8) * 64);
    __syncthreads();

    // prefetch next K-step's B fragments (complete under MFMA shadow)
    const int k1 = (k0 + 64 < K_DIM) ? k0 + 64 : k0;
#pragma unroll
    for (int kki = 0; kki < 4; kki++) {
      bbn[0][kki] = *(const bf16x8*)(Bp0 + k1 + kki * 16);
      bbn[1][kki] = *(const bf16x8*)(Bp1 + k1 + kki * 16);
    }

#pragma unroll
    for (int kki = 0; kki < 4; kki++) {
      const int ch = (((2 * kki + l5) ^ l7) << 3);   // swizzled chunk
      bf16x8 af[2];
#pragma unroll
      for (int f = 0; f < 2; f++)
        af[f] = *(const bf16x8*)(As + (wm + f * 32 + l31) * 64 + ch);
#pragma unroll
      for (int fm = 0; fm < 2; fm++)
#pragma unroll
        for (int fn = 0; fn < 2; fn++)
          acc[fm][fn] = __builtin_amdgcn_mfma_f32_32x32x16_bf16(af[fm], bb[fn][kki], acc[fm][fn], 0, 0, 0);
    }
    __syncthreads();

#pragma unroll
    for (int kki = 0; kki < 4; kki++) {
      bb[0][kki] = bbn[0][kki];
      bb[1][kki] = bbn[1][kki];
    }
  }

  // epilogue: C/D layout col=lane&31, row=(reg&3)+8*(reg>>2)+4*(lane>>5)
#pragma unroll
  for (int fm = 0; fm < 2; fm++) {
#pragma unroll
    for (int fn = 0; fn < 2; fn++) {
      const int colb = col0 + wn + fn * 32 + l31;
      const int rowb = row0 + wm + fm * 32 + 4 * l5;
#pragma unroll
      for (int reg = 0; reg < 16; reg++) {
        int row = rowb + (reg & 3) + 8 * (reg >> 2);
        C[row * N_COLS + colb] = acc[fm][fn][reg];
      }
    }
  }
}

// ---------------------------------------------------------------- launch
extern "C" void kernel_launch(void* const* d_in, const int* in_sizes, int n_in,
                              void* d_out, int out_size, void* d_ws, size_t ws_size,
                              hipStream_t stream) {
  const float* x  = (const float*)d_in[0];   // 32*512*10
  const float* qp = (const float*)d_in[1];   // 10
  const float* W1 = (const float*)d_in[2];   // 4096*10
  const float* W2 = (const float*)d_in[3];   // 1024*4096
  float* out = (float*)d_out;                // 32*512*1024 fp32

  char* ws = (char*)d_ws;
  float*          W1T = (float*)ws;                                  // 163840 B
  __hip_bfloat16* W2b = (__hip_bfloat16*)(ws + 163840);              // 8388608 B
  __hip_bfloat16* hbf = (__hip_bfloat16*)(ws + 163840 + 8388608);    // 134217728 B

  prep<<<4112, 256, 0, stream>>>(W1, W1T, W2, W2b);
  compute_h<<<M_ROWS / 8, 256, 0, stream>>>(x, qp, W1T, hbf);
  gemm_bt<<<(N_COLS / 128) * (M_ROWS / 128), 256, 0, stream>>>(hbf, W2b, out);
}

// Round 5
// 248.675 us; speedup vs baseline: 1.6248x; 1.6248x over previous
//
#include <hip/hip_runtime.h>
#include <hip/hip_bf16.h>

typedef __bf16 bf16x8 __attribute__((ext_vector_type(8)));
typedef float f32x16 __attribute__((ext_vector_type(16)));

#define NQ     10
#define M_ROWS 16384
#define N_COLS 1024
#define K_DIM  4096

// ---------------------------------------------------------------- helpers
__device__ __forceinline__ void gload_lds16(const __hip_bfloat16* g, __hip_bfloat16* l) {
  __builtin_amdgcn_global_load_lds(
      (const __attribute__((address_space(1))) void*)g,
      (__attribute__((address_space(3))) void*)l,
      16, 0, 0);
}

// ---------------------------------------------------------------- prep (fused)
// blocks 0..4095: W2 fp32->bf16 ; blocks 4096..4111: W1 (4096x10) -> W1T (10x4096)
__global__ void __launch_bounds__(256) prep(const float* __restrict__ W1,
                                            float* __restrict__ W1T,
                                            const float* __restrict__ W2,
                                            __hip_bfloat16* __restrict__ W2b) {
  const int b = blockIdx.x;
  if (b < 4096) {
    int i = (b * 256 + threadIdx.x) * 4;
    float4 v = *(const float4*)(W2 + i);
    union { __hip_bfloat16 h[4]; uint2 u; } p;
    p.h[0] = __float2bfloat16(v.x);
    p.h[1] = __float2bfloat16(v.y);
    p.h[2] = __float2bfloat16(v.z);
    p.h[3] = __float2bfloat16(v.w);
    *(uint2*)(W2b + i) = p.u;
  } else {
    int f = (b - 4096) * 256 + threadIdx.x;
#pragma unroll
    for (int j = 0; j < NQ; j++)
      W1T[j * K_DIM + f] = W1[f * NQ + j];
  }
}

// ---------------------------------------------------------------- h = relu(q_out @ W1^T) bf16
// closed form: q[0] = prod_{j=1..9} cos; q[k] = prod_{j=0..k} cos
__global__ void __launch_bounds__(256) compute_h(const float* __restrict__ x,
                                                 const float* __restrict__ qp,
                                                 const float* __restrict__ W1T,
                                                 __hip_bfloat16* __restrict__ h) {
  __shared__ float qs[8][NQ];
  const int tid = threadIdx.x;
  const int r0 = blockIdx.x * 8;

  if (tid < 8 * NQ) {
    int r = tid / NQ, j = tid % NQ;
    qs[r][j] = cosf(x[(r0 + r) * NQ + j] + qp[j]);
  }
  __syncthreads();
  if (tid < 8) {
    float c[NQ];
#pragma unroll
    for (int j = 0; j < NQ; j++) c[j] = qs[tid][j];
    float pref = c[0];
    float prod19 = 1.f;
#pragma unroll
    for (int j = 1; j < NQ; j++) prod19 *= c[j];
    qs[tid][0] = prod19;
#pragma unroll
    for (int k = 1; k < NQ; k++) { pref *= c[k]; qs[tid][k] = pref; }
  }
  __syncthreads();

#pragma unroll 1
  for (int k = 0; k < 2; k++) {
    const int col0 = k * 2048 + tid * 8;
    float w[8][NQ];
#pragma unroll
    for (int j = 0; j < NQ; j++) {
      float4 a = *(const float4*)(W1T + j * K_DIM + col0);
      float4 b = *(const float4*)(W1T + j * K_DIM + col0 + 4);
      w[0][j] = a.x; w[1][j] = a.y; w[2][j] = a.z; w[3][j] = a.w;
      w[4][j] = b.x; w[5][j] = b.y; w[6][j] = b.z; w[7][j] = b.w;
    }
#pragma unroll
    for (int r = 0; r < 8; r++) {
      float q[NQ];
#pragma unroll
      for (int j = 0; j < NQ; j++) q[j] = qs[r][j];
      union { __hip_bfloat16 hh[8]; uint4 u; } pk;
#pragma unroll
      for (int c = 0; c < 8; c++) {
        float acc = 0.f;
#pragma unroll
        for (int j = 0; j < NQ; j++) acc = fmaf(q[j], w[c][j], acc);
        pk.hh[c] = __float2bfloat16(fmaxf(acc, 0.f));
      }
      *(uint4*)(h + (r0 + r) * K_DIM + col0) = pk.u;
    }
  }
}

// ---------------------------------------------------------------- C = A(MxK) * B(NxK)^T, bf16 in fp32 out
// 256x128 block tile, 4 waves with 128x64 wave tiles (4x2 frags of 32x32x16):
// LDS-read:MFMA ratio 0.75 vs 1.0 for 64x64 tiles — the LDS pipe was the
// round-3 limiter. Both operands through LDS (round-4's direct-B gather
// regressed 2x). XOR slot swizzle; 48 KB LDS; 2 blocks/CU.
__global__ void __launch_bounds__(256, 2) gemm_bt(const __hip_bfloat16* __restrict__ A,
                                                  const __hip_bfloat16* __restrict__ B,
                                                  float* __restrict__ C) {
  __shared__ __align__(16) __hip_bfloat16 As[256 * 64];   // 32 KB
  __shared__ __align__(16) __hip_bfloat16 Bs[128 * 64];   // 16 KB

  const int tid  = threadIdx.x;
  const int wave = tid >> 6;
  const int lane = tid & 63;
  const int l31  = lane & 31;
  const int l5   = lane >> 5;
  const int l7   = l31 & 7;
  const int wm   = (wave & 1) * 128;   // wave tile 128x64
  const int wn   = (wave >> 1) * 64;

  // XCD decode: XCD d owns rows [d*2048, d*2048+2048) x all 8 col-tiles
  const int L    = blockIdx.x;           // 512 blocks
  const int xcd  = L & 7;
  const int idx  = L >> 3;               // 0..63
  const int col0 = (idx >> 3) * 128;     // 8 col tiles, slow
  const int row0 = ((xcd << 3) | (idx & 7)) * 256;

  const int ldrow = lane >> 3;                       // 0..7 within 8-row group
  const int ldc   = (((lane & 7) ^ ldrow) << 3);     // XOR slot: chunk c of row r at slot c^(r&7)

  f32x16 acc[4][2];
#pragma unroll
  for (int i = 0; i < 4; i++)
#pragma unroll
    for (int j = 0; j < 2; j++)
#pragma unroll
      for (int r = 0; r < 16; r++) acc[i][j][r] = 0.f;

  for (int k0 = 0; k0 < K_DIM; k0 += 64) {
    // stage A (256x64): 8 instrs/wave; wave w covers rows 64w..64w+63
#pragma unroll
    for (int i = 0; i < 8; i++)
      gload_lds16(A + (row0 + wave * 64 + i * 8 + ldrow) * K_DIM + k0 + ldc,
                  As + (wave * 8 + i) * 512);
    // stage B (128x64): 4 instrs/wave; wave w covers rows 32w..32w+31
#pragma unroll
    for (int i = 0; i < 4; i++)
      gload_lds16(B + (col0 + wave * 32 + i * 8 + ldrow) * K_DIM + k0 + ldc,
                  Bs + (wave * 4 + i) * 512);
    __syncthreads();

#pragma unroll
    for (int kki = 0; kki < 4; kki++) {
      const int ch = (((2 * kki + l5) ^ l7) << 3);   // physical slot
      bf16x8 af[4], bb[2];
#pragma unroll
      for (int f = 0; f < 4; f++)
        af[f] = *(const bf16x8*)(As + (wm + f * 32 + l31) * 64 + ch);
#pragma unroll
      for (int f = 0; f < 2; f++)
        bb[f] = *(const bf16x8*)(Bs + (wn + f * 32 + l31) * 64 + ch);
#pragma unroll
      for (int fm = 0; fm < 4; fm++)
#pragma unroll
        for (int fn = 0; fn < 2; fn++)
          acc[fm][fn] = __builtin_amdgcn_mfma_f32_32x32x16_bf16(af[fm], bb[fn], acc[fm][fn], 0, 0, 0);
    }
    __syncthreads();
  }

  // epilogue: C/D layout col=lane&31, row=(reg&3)+8*(reg>>2)+4*(lane>>5)
#pragma unroll
  for (int fm = 0; fm < 4; fm++) {
#pragma unroll
    for (int fn = 0; fn < 2; fn++) {
      const int colb = col0 + wn + fn * 32 + l31;
      const int rowb = row0 + wm + fm * 32 + 4 * l5;
#pragma unroll
      for (int reg = 0; reg < 16; reg++) {
        int row = rowb + (reg & 3) + 8 * (reg >> 2);
        C[row * N_COLS + colb] = acc[fm][fn][reg];
      }
    }
  }
}

// ---------------------------------------------------------------- launch
extern "C" void kernel_launch(void* const* d_in, const int* in_sizes, int n_in,
                              void* d_out, int out_size, void* d_ws, size_t ws_size,
                              hipStream_t stream) {
  const float* x  = (const float*)d_in[0];   // 32*512*10
  const float* qp = (const float*)d_in[1];   // 10
  const float* W1 = (const float*)d_in[2];   // 4096*10
  const float* W2 = (const float*)d_in[3];   // 1024*4096
  float* out = (float*)d_out;                // 32*512*1024 fp32

  char* ws = (char*)d_ws;
  float*          W1T = (float*)ws;                                  // 163840 B
  __hip_bfloat16* W2b = (__hip_bfloat16*)(ws + 163840);              // 8388608 B
  __hip_bfloat16* hbf = (__hip_bfloat16*)(ws + 163840 + 8388608);    // 134217728 B

  prep<<<4112, 256, 0, stream>>>(W1, W1T, W2, W2b);
  compute_h<<<M_ROWS / 8, 256, 0, stream>>>(x, qp, W1T, hbf);
  gemm_bt<<<(M_ROWS / 256) * (N_COLS / 128), 256, 0, stream>>>(hbf, W2b, out);
}

// Round 6
// 225.433 us; speedup vs baseline: 1.7923x; 1.1031x over previous
//
#include <hip/hip_runtime.h>
#include <hip/hip_bf16.h>

typedef __bf16 bf16x8 __attribute__((ext_vector_type(8)));
typedef float f32x16 __attribute__((ext_vector_type(16)));

#define NQ     10
#define M_ROWS 16384
#define N_COLS 1024
#define K_DIM  4096

// ---------------------------------------------------------------- helpers
__device__ __forceinline__ void gload_lds16(const __hip_bfloat16* g, __hip_bfloat16* l) {
  __builtin_amdgcn_global_load_lds(
      (const __attribute__((address_space(1))) void*)g,
      (__attribute__((address_space(3))) void*)l,
      16, 0, 0);
}

// ---------------------------------------------------------------- prep (fused)
// blocks [0,4096): W2 fp32->bf16
// blocks [4096,4112): Wq[kcol][0..15] = bf16(W1[kcol][j]) (j<10), 0 pad
// blocks [4112,4176): Qb[row][0..15]  = bf16(q_j(row)) closed-form, 0 pad
//   q[0] = prod_{j=1..9} cos(th_j); q[k] = prod_{j=0..k} cos(th_j)
__global__ void __launch_bounds__(256) prep(const float* __restrict__ W1,
                                            const float* __restrict__ W2,
                                            const float* __restrict__ x,
                                            const float* __restrict__ qp,
                                            __hip_bfloat16* __restrict__ W2b,
                                            __hip_bfloat16* __restrict__ Wq,
                                            __hip_bfloat16* __restrict__ Qb) {
  const int b = blockIdx.x;
  const int tid = threadIdx.x;
  if (b < 4096) {
    int i = (b * 256 + tid) * 4;
    float4 v = *(const float4*)(W2 + i);
    union { __hip_bfloat16 h[4]; uint2 u; } p;
    p.h[0] = __float2bfloat16(v.x);
    p.h[1] = __float2bfloat16(v.y);
    p.h[2] = __float2bfloat16(v.z);
    p.h[3] = __float2bfloat16(v.w);
    *(uint2*)(W2b + i) = p.u;
  } else if (b < 4112) {
    int kcol = (b - 4096) * 256 + tid;
    union { __hip_bfloat16 h[16]; uint4 u[2]; } p;
#pragma unroll
    for (int j = 0; j < NQ; j++) p.h[j] = __float2bfloat16(W1[kcol * NQ + j]);
#pragma unroll
    for (int j = NQ; j < 16; j++) p.h[j] = __float2bfloat16(0.f);
    *(uint4*)(Wq + kcol * 16) = p.u[0];
    *(uint4*)(Wq + kcol * 16 + 8) = p.u[1];
  } else {
    int row = (b - 4112) * 256 + tid;
    float c[NQ];
#pragma unroll
    for (int j = 0; j < NQ; j++) c[j] = cosf(x[row * NQ + j] + qp[j]);
    float q[NQ];
    float prod19 = 1.f;
#pragma unroll
    for (int j = 1; j < NQ; j++) prod19 *= c[j];
    q[0] = prod19;
    float pref = c[0];
#pragma unroll
    for (int k = 1; k < NQ; k++) { pref *= c[k]; q[k] = pref; }
    union { __hip_bfloat16 h[16]; uint4 u[2]; } p;
#pragma unroll
    for (int j = 0; j < NQ; j++) p.h[j] = __float2bfloat16(q[j]);
#pragma unroll
    for (int j = NQ; j < 16; j++) p.h[j] = __float2bfloat16(0.f);
    *(uint4*)(Qb + row * 16) = p.u[0];
    *(uint4*)(Qb + row * 16 + 8) = p.u[1];
  }
}

// ---------------------------------------------------------------- fused gemm
// C = relu(Q @ W1^T) @ W2^T. A-tiles (h) are never materialized in HBM:
// per block-K-step, 16 mini-MFMAs (32x32x16, K=16>=10 qubits) compute the
// 256x64 h-tile from Qb/Wq and ds_write it (relu+bf16) straight into the
// XOR-swizzled As layout the main loop reads. Saves 134 MB h write +
// 134 MB h read + the whole compute_h kernel (~50 us).
// Main loop: 256x128 block tile, 4 waves x 128x64 wave tiles, 32x32x16 MFMA.
__global__ void __launch_bounds__(256, 2) gemm_fused(const __hip_bfloat16* __restrict__ Qb,
                                                     const __hip_bfloat16* __restrict__ Wq,
                                                     const __hip_bfloat16* __restrict__ B,
                                                     float* __restrict__ C) {
  __shared__ __align__(16) __hip_bfloat16 As[256 * 64];   // 32 KB
  __shared__ __align__(16) __hip_bfloat16 Bs[128 * 64];   // 16 KB

  const int tid  = threadIdx.x;
  const int wave = tid >> 6;
  const int lane = tid & 63;
  const int l31  = lane & 31;
  const int l5   = lane >> 5;
  const int l7   = l31 & 7;
  const int wm   = (wave & 1) * 128;   // wave tile 128x64
  const int wn   = (wave >> 1) * 64;

  // XCD decode: XCD d owns rows [d*2048, d*2048+2048) x all 8 col-tiles
  const int L    = blockIdx.x;           // 512 blocks
  const int xcd  = L & 7;
  const int idx  = L >> 3;               // 0..63
  const int col0 = (idx >> 3) * 128;     // 8 col tiles, slow
  const int row0 = ((xcd << 3) | (idx & 7)) * 256;

  const int ldrow = lane >> 3;                       // staging row 0..7
  const int ldc   = (((lane & 7) ^ ldrow) << 3);     // XOR slot for Bs staging

  // mini-GEMM B-operand frags (loop-invariant): Qb[hrow = row0+rg*32+l31][q = l5*8+j]
  bf16x8 qb[2];
#pragma unroll
  for (int i = 0; i < 2; i++)
    qb[i] = *(const bf16x8*)(Qb + (row0 + (2 * wave + i) * 32 + l31) * 16 + l5 * 8);

  f32x16 acc[4][2];
#pragma unroll
  for (int i = 0; i < 4; i++)
#pragma unroll
    for (int j = 0; j < 2; j++)
#pragma unroll
      for (int r = 0; r < 16; r++) acc[i][j][r] = 0.f;

  for (int k0 = 0; k0 < K_DIM; k0 += 64) {
    // stage Bs (async, drains at the barrier)
#pragma unroll
    for (int i = 0; i < 4; i++)
      gload_lds16(B + (col0 + wave * 32 + i * 8 + ldrow) * K_DIM + k0 + ldc,
                  Bs + (wave * 4 + i) * 512);

    // mini-GEMM A-operand frags: Wq[kcol = k0+kt*32+l31][q = l5*8+j]
    bf16x8 wq[2];
#pragma unroll
    for (int kt = 0; kt < 2; kt++)
      wq[kt] = *(const bf16x8*)(Wq + (k0 + kt * 32 + l31) * 16 + l5 * 8);

    // compute h-tile into As: D[kcol][hrow], lane<->hrow, regs<->kcol quads
#pragma unroll
    for (int kt = 0; kt < 2; kt++) {
#pragma unroll
      for (int i = 0; i < 2; i++) {
        f32x16 d;
#pragma unroll
        for (int r = 0; r < 16; r++) d[r] = 0.f;
        d = __builtin_amdgcn_mfma_f32_32x32x16_bf16(wq[kt], qb[i], d, 0, 0, 0);
        const int hrow = (2 * wave + i) * 32 + l31;
#pragma unroll
        for (int q = 0; q < 4; q++) {
          // regs 4q..4q+3 -> kcols kt*32 + 8q + 4*l5 + {0..3}; chunk = kt*4+q
          union { __hip_bfloat16 h[4]; ushort4 u; } p;
#pragma unroll
          for (int r = 0; r < 4; r++)
            p.h[r] = __float2bfloat16(fmaxf(d[4 * q + r], 0.f));
          const int slot = (kt * 4 + q) ^ (l31 & 7);
          *(ushort4*)(As + hrow * 64 + slot * 8 + 4 * l5) = p.u;
        }
      }
    }
    __syncthreads();

    // main MFMA loop
#pragma unroll
    for (int kki = 0; kki < 4; kki++) {
      const int ch = (((2 * kki + l5) ^ l7) << 3);   // physical slot
      bf16x8 af[4], bb[2];
#pragma unroll
      for (int f = 0; f < 4; f++)
        af[f] = *(const bf16x8*)(As + (wm + f * 32 + l31) * 64 + ch);
#pragma unroll
      for (int f = 0; f < 2; f++)
        bb[f] = *(const bf16x8*)(Bs + (wn + f * 32 + l31) * 64 + ch);
#pragma unroll
      for (int fm = 0; fm < 4; fm++)
#pragma unroll
        for (int fn = 0; fn < 2; fn++)
          acc[fm][fn] = __builtin_amdgcn_mfma_f32_32x32x16_bf16(af[fm], bb[fn], acc[fm][fn], 0, 0, 0);
    }
    __syncthreads();
  }

  // epilogue: C/D layout col=lane&31, row=(reg&3)+8*(reg>>2)+4*(lane>>5)
#pragma unroll
  for (int fm = 0; fm < 4; fm++) {
#pragma unroll
    for (int fn = 0; fn < 2; fn++) {
      const int colb = col0 + wn + fn * 32 + l31;
      const int rowb = row0 + wm + fm * 32 + 4 * l5;
#pragma unroll
      for (int reg = 0; reg < 16; reg++) {
        int row = rowb + (reg & 3) + 8 * (reg >> 2);
        C[row * N_COLS + colb] = acc[fm][fn][reg];
      }
    }
  }
}

// ---------------------------------------------------------------- launch
extern "C" void kernel_launch(void* const* d_in, const int* in_sizes, int n_in,
                              void* d_out, int out_size, void* d_ws, size_t ws_size,
                              hipStream_t stream) {
  const float* x  = (const float*)d_in[0];   // 32*512*10
  const float* qp = (const float*)d_in[1];   // 10
  const float* W1 = (const float*)d_in[2];   // 4096*10
  const float* W2 = (const float*)d_in[3];   // 1024*4096
  float* out = (float*)d_out;                // 32*512*1024 fp32

  char* ws = (char*)d_ws;
  __hip_bfloat16* W2b = (__hip_bfloat16*)ws;                 // 8388608 B
  __hip_bfloat16* Wq  = (__hip_bfloat16*)(ws + 8388608);     // 131072 B (4096x16)
  __hip_bfloat16* Qb  = (__hip_bfloat16*)(ws + 8519680);     // 524288 B (16384x16)

  prep<<<4176, 256, 0, stream>>>(W1, W2, x, qp, W2b, Wq, Qb);
  gemm_fused<<<(M_ROWS / 256) * (N_COLS / 128), 256, 0, stream>>>(Qb, Wq, W2b, out);
}